// Round 4
// baseline (418.916 us; speedup 1.0000x reference)
//
#include <hip/hip_runtime.h>
#include <hip/hip_bf16.h>

// AdaptiveGraphConvolution on MI355X — round 6.
// N=64, C=64, T=300, V=25, S=3 subsets, IC=16, O=64.
//
// Round-5 post-mortem: launch_bounds(256,4) set waves-per-eu MIN=4 with no
// max; the allocator targeted 8 waves/EU (64 VGPRs) and spilled the T14
// prefetch registers to scratch: WRITE_SIZE 15->92 MB, FETCH 67->144 MB
// (+77 MB each way = spill store+reload arithmetic), k1 101->107 us.
// Round-6 fix (k1 only):
//  * amdgpu_waves_per_eu(4,4): pin occupancy target to 4 waves/EU
//    (VGPR budget 128); LDS already caps at 4 blocks/CU so nothing lost.
//  * drop goff[7]/xps[7] precomputed arrays (-14 VGPRs); recompute the
//    idx/25 addressing inline each use (magic-mul; VALUBusy is at 10%).
//  Live set ~105 VGPRs < 128 -> no spill.
// k0/k2/k3 unchanged from round 5.

#define NB 64
#define CB 64
#define TB 300
#define VB 25

typedef unsigned int uint32;
typedef unsigned short ushort16;
typedef __attribute__((ext_vector_type(8))) short short8;
typedef __attribute__((ext_vector_type(4))) float f32x4;
typedef __attribute__((ext_vector_type(16))) float f32x16;

__device__ __forceinline__ ushort16 f2bf(float f) {
    __hip_bfloat16 h = __float2bfloat16(f);
    ushort16 u;
    __builtin_memcpy(&u, &h, sizeof(u));
    return u;
}
__device__ __forceinline__ float bf2f(ushort16 h) {
    return __uint_as_float(((uint32)h) << 16);
}
__device__ __forceinline__ uint32 packbf2(float a, float b) {
    return (uint32)f2bf(a) | ((uint32)f2bf(b) << 16);
}

// ---------------------------------------------------------------- kernel 0
// one-time weight prep. grid 48 x 256.
//   idx <  6144: W bf16, layout [kb8][r][8]:  wb2[(kb*96+r)*8+ci] = W[r][kb*8+ci]
//   idx < 12288: g_w -> gwb bf16 pairs (k3 A-operand layout)
__global__ __launch_bounds__(256) void k0_prep(
    const float* __restrict__ a_w, const float* __restrict__ b_w,
    const float* __restrict__ g_w,
    ushort16* __restrict__ wb2, uint32* __restrict__ gwb)
{
    int idx = blockIdx.x * 256 + threadIdx.x;
    if (idx < 6144) {
        int kb = idx / 768, rem = idx % 768;
        int r = rem >> 3, ci = rem & 7;
        int c = kb * 8 + ci;
        float v = (r < 48) ? a_w[r * 64 + c] : b_w[(r - 48) * 64 + c];
        wb2[idx] = f2bf(v);
    } else if (idx < 12288) {
        int j = idx - 6144;
        int o = j / 96, kp = j % 96;
        int k0 = 2 * kp, i = k0 >> 6, c = k0 & 63;
        float2 lh = *(const float2*)(g_w + (i * 64 + o) * 64 + c);
        gwb[j] = packbf2(lh.x, lh.y);
    }
}

// ---------------------------------------------------------------- kernel 1
// grid 1600 = 64 n * 25 chunks (12 t), 256 thr = 4 waves, 4 blocks/CU
__global__ __attribute__((amdgpu_waves_per_eu(4, 4)))
__launch_bounds__(256) void k1_attn_logits_mfma(
    const float* __restrict__ x, const ushort16* __restrict__ wb2,
    const float* __restrict__ a_b, const float* __restrict__ b_b,
    float* __restrict__ Mb)
{
    // pool: xT[126 rows][64] (rows >=100 read-only garbage, reads for
    // tv 126/127 spill into abT rows 0/1 -> discarded cols), then
    // abT[192 rows][64]. Total 40704 B -> 4 blocks/CU.
    __shared__ ushort16 pool[20352];
    ushort16* xT  = pool;
    ushort16* abT = pool + 126 * 64;

    const int tid   = threadIdx.x;
    const int n     = blockIdx.x / 25;
    const int chunk = blockIdx.x % 25;
    const float* xn = x + n * (CB * TB * VB);

    // bias stash: f32 in abT rows 31/63/95 (phase-B reads of rows v>=25
    // produce discarded outputs; phase-A writes only touch v<25).
    if (tid < 96) {
        float v = (tid < 48) ? a_b[tid] : b_b[tid - 48];
        ((float*)(abT + (31 + (tid >> 5) * 32) * 64))[tid & 31] = v;
    }

    const int w    = tid >> 6;
    const int lane = tid & 63;
    const int hi   = lane >> 5;
    const int v32  = lane & 31;

    const float* xb0 = xn + chunk * 12 * 25;

    // prologue prefetch (T14): sub-chunk 0
    float4 pf[7];
    #pragma unroll
    for (int k = 0; k < 7; ++k) {
        int idx = tid + k * 256;
        if (idx < 1600) {
            int c = idx / 25, j = idx - c * 25;
            pf[k] = *(const float4*)(xb0 + c * 7500 + j * 4);
        }
    }

    // phase-A hoists: wave w owns col-tile ct=w
    const int tv     = w * 32 + v32;
    const bool avalid = tv < 100;
    const int tl = tv / 25;
    const int vv = tv - tl * 25;

    f32x16 accB;
    #pragma unroll
    for (int r = 0; r < 16; ++r) accB[r] = 0.f;

    for (int s = 0; s < 3; ++s) {
        __syncthreads();   // phase A/B of s-1 done with xT/abT
        // ---- write xT from prefetched regs
        // row tv = 4j+e, swizzle block = ((c>>3) + tv + (tv>>2)) & 7
        //   = ((c>>3) + 5j + e) & 7  since (4j+e)>>2 == j for e<4.
        #pragma unroll
        for (int k = 0; k < 7; ++k) {
            int idx = tid + k * 256;
            if (idx < 1600) {
                int c = idx / 25, j = idx - c * 25;
                int sb = ((c >> 3) + 5 * j) & 7;
                int base = (4 * j) * 64 + (c & 7);
                float4 v4 = pf[k];
                xT[base + 0 * 64 + (((sb + 0) & 7) << 3)] = f2bf(v4.x);
                xT[base + 1 * 64 + (((sb + 1) & 7) << 3)] = f2bf(v4.y);
                xT[base + 2 * 64 + (((sb + 2) & 7) << 3)] = f2bf(v4.z);
                xT[base + 3 * 64 + (((sb + 3) & 7) << 3)] = f2bf(v4.w);
            }
        }
        // ---- issue next sub-chunk loads (complete during phase A/B)
        if (s < 2) {
            const float* xbn = xb0 + (s + 1) * 100;
            #pragma unroll
            for (int k = 0; k < 7; ++k) {
                int idx = tid + k * 256;
                if (idx < 1600) {
                    int c = idx / 25, j = idx - c * 25;
                    pf[k] = *(const float4*)(xbn + c * 7500 + j * 4);
                }
            }
        }
        __syncthreads();
        // ---- phase A: ab = W @ x on 32x32x16; 3 rt tiles, ct = w
        #pragma unroll
        for (int rt = 0; rt < 3; ++rt) {
            f32x16 d;
            #pragma unroll
            for (int r = 0; r < 16; ++r) d[r] = 0.f;
            #pragma unroll
            for (int k16 = 0; k16 < 4; ++k16) {
                int kb = k16 * 2 + hi;
                short8 af = *(const short8*)(wb2 + (kb * 96 + rt * 32 + v32) * 8);
                short8 bf = *(const short8*)&xT[tv * 64 +
                                                (((kb + tv + (tv >> 2)) & 7) << 3)];
                d = __builtin_amdgcn_mfma_f32_32x32x16_bf16(af, bf, d, 0, 0, 0);
            }
            if (avalid) {
                #pragma unroll
                for (int a = 0; a < 4; ++a) {
                    int rowoff = 8 * a + 4 * hi;            // D row within 32
                    int g   = rt * 2 + (rowoff >> 4);       // abT group
                    int icb = rowoff & 15;
                    float4 bq = *(const float4*)(
                        (const float*)(abT + (31 + rt * 32) * 64) + rowoff);
                    int kbw = tl * 2 + (icb >> 3);
                    uint32* dst = (uint32*)&abT[(g * 32 + vv) * 64 +
                                                (((kbw + vv) & 7) << 3) + (icb & 7)];
                    dst[0] = packbf2(d[4 * a + 0] + bq.x, d[4 * a + 1] + bq.y);
                    dst[1] = packbf2(d[4 * a + 2] + bq.z, d[4 * a + 3] + bq.w);
                }
            }
        }
        __syncthreads();
        // ---- phase B: wave w (<3) owns subset i=w, all 4 local t
        if (w < 3) {
            #pragma unroll
            for (int tl2 = 0; tl2 < 4; ++tl2) {
                int kb = tl2 * 2 + hi;
                short8 af = *(const short8*)&abT[(w * 32 + v32) * 64 +
                                                 (((kb + v32) & 7) << 3)];
                short8 bf = *(const short8*)&abT[((3 + w) * 32 + v32) * 64 +
                                                 (((kb + v32) & 7) << 3)];
                accB = __builtin_amdgcn_mfma_f32_32x32x16_bf16(af, bf, accB, 0, 0, 0);
            }
        }
    }

    // ---- tail: each wave holds a full M_i -> atomics straight from regs
    if (w < 3 && v32 < 25) {
        const float inv = 1.0f / 4800.0f;
        #pragma unroll
        for (int r = 0; r < 16; ++r) {
            int row = (r & 3) + 8 * (r >> 2) + 4 * hi;   // m74/m101 C-layout
            if (row < 25)
                atomicAdd(Mb + ((w * NB + n) * 25 + row) * 25 + v32, accB[r] * inv);
        }
    }
}

// ---------------------------------------------------------------- kernel 2
// 192 blocks = (i,n); softmax over v1 + A_tot -> atT bf16 [i][n][v2][v1 pad32]
__global__ __launch_bounds__(128) void k2_softmax(
    const float* __restrict__ Mb, const float* __restrict__ A,
    const float* __restrict__ GA, uint32* __restrict__ atT)
{
    __shared__ float Ms[640];
    const int b   = blockIdx.x;
    const int tid = threadIdx.x;
    const int i = b >> 6, n = b & 63;
    const float* src = Mb + b * 625;       // [i][n] tile, contiguous
    for (int idx = tid; idx < 625; idx += 128) Ms[idx] = src[idx];
    __syncthreads();
    if (tid < 25) {
        const int v2 = tid;
        float e[25], mx = -1e30f;
        #pragma unroll
        for (int v1 = 0; v1 < 25; ++v1) {
            e[v1] = Ms[v1 * 25 + v2];
            mx = fmaxf(mx, e[v1]);
        }
        float s = 0.f;
        #pragma unroll
        for (int v1 = 0; v1 < 25; ++v1) { e[v1] = __expf(e[v1] - mx); s += e[v1]; }
        float invs = 1.0f / s;
        const float* acol = A + i * 625 + v2;
        const float* gcol = GA + i * 625 + v2;
        float wv[25];
        #pragma unroll
        for (int v1 = 0; v1 < 25; ++v1)
            wv[v1] = e[v1] * invs + acol[v1 * 25] + gcol[v1 * 25];
        uint32* row = atT + ((i * 64 + n) * 32 + v2) * 16;
        #pragma unroll
        for (int p = 0; p < 12; ++p) row[p] = packbf2(wv[2 * p], wv[2 * p + 1]);
        row[12] = (uint32)f2bf(wv[24]);
        row[13] = 0u; row[14] = 0u; row[15] = 0u;
    }
}

// ---------------------------------------------------------------- kernel 3
// MFMA. grid 3840 = 64 n * 60 chunks of 5 t; 256 thr = 4 waves (wave=o/c tile)
__global__ __launch_bounds__(256) void k3_out(
    const float* __restrict__ x, const uint32* __restrict__ atT,
    const ushort16* __restrict__ gwb, const float* __restrict__ g_b,
    const float* __restrict__ bn_g, const float* __restrict__ bn_b,
    const float* __restrict__ bn_m, const float* __restrict__ bn_v,
    float* __restrict__ out)
{
    __shared__ ushort16 xs[64 * 168];   // [c][t*32 + v1]  (stride 168: 2-way banks)
    __shared__ uint32  xa[128 * 36];    // [col=(t,v2) pad128][c: 72 bf16 as 36 u32]
    __shared__ uint32  ats[3 * 32 * 20];// [i][v2][v1: 40 bf16 as 20 u32]
    __shared__ float   bsc[64], bsh[64];

    const int tid = threadIdx.x;
    const int n  = blockIdx.x / 60;
    const int t0 = (blockIdx.x % 60) * 5;

    // stage x tile -> bf16 [c][t][v1]
    for (int idx = tid; idx < 8000; idx += 256) {
        int c = idx / 125, tv = idx % 125;
        int t = tv / 25, v = tv % 25;
        float g = x[((n * 64 + c) * 300 + t0 + t) * 25 + v];
        xs[c * 168 + t * 32 + v] = f2bf(g);
    }
    for (int idx = tid; idx < 64 * 35; idx += 256) {   // zero v1 in [25,32)
        int c = idx / 35, r = idx % 35;
        xs[c * 168 + (r / 7) * 32 + 25 + (r % 7)] = (ushort16)0;
    }
    // stage attn^T rows for this n
    for (int idx = tid; idx < 1536; idx += 256) {
        int row = idx >> 4, d = idx & 15;   // row = i*32+v2
        ats[row * 20 + d] = atT[((row >> 5) * 64 + n) * 512 + (row & 31) * 16 + d];
    }
    // BN scale/shift prefold (h = acc*sc + sh + x)
    for (int idx = tid; idx < 64; idx += 256) {
        float sc = bn_g[idx] * rsqrtf(bn_v[idx] + 1e-5f);
        bsc[idx] = sc;
        bsh[idx] = (g_b[idx] + g_b[64 + idx] + g_b[128 + idx] - bn_m[idx]) * sc + bn_b[idx];
    }
    // zero xa pad rows (cols 125..127)
    for (int idx = tid; idx < 3 * 36; idx += 256)
        xa[(125 + idx / 36) * 36 + idx % 36] = 0u;

    const int w    = tid >> 6;      // wave id = o-tile (main) = c-tile (xa)
    const int lane = tid & 63;
    const int l15  = lane & 15;
    const int q    = lane >> 4;

    // preload A-frags of gw (all 6 K-steps: k = i*64 + s*32)
    short8 gf[6];
    #pragma unroll
    for (int s = 0; s < 6; ++s)
        gf[s] = *(const short8*)(gwb + ((w * 16 + l15) * 192 + s * 32 + q * 8));

    f32x4 acc[8];
    #pragma unroll
    for (int ct = 0; ct < 8; ++ct) acc[ct] = (f32x4){0.f, 0.f, 0.f, 0.f};
    const f32x4 zf = (f32x4){0.f, 0.f, 0.f, 0.f};

    __syncthreads();

    for (int i = 0; i < 3; ++i) {
        if (i) __syncthreads();   // previous xa fully consumed
        // ---- xa-phase: this wave produces c-rows [w*16, w*16+16)
        #pragma unroll
        for (int t = 0; t < 5; ++t) {
            short8 ax = *(const short8*)(xs + (w * 16 + l15) * 168 + t * 32 + q * 8);
            #pragma unroll
            for (int vt = 0; vt < 2; ++vt) {
                short8 bt = *(const short8*)((const ushort16*)ats +
                                             (i * 32 + vt * 16 + l15) * 40 + q * 8);
                f32x4 d = __builtin_amdgcn_mfma_f32_16x16x32_bf16(ax, bt, zf, 0, 0, 0);
                int v2 = vt * 16 + l15;
                if (v2 < 25) {
                    int col = t * 25 + v2;
                    int c0  = w * 16 + q * 4;
                    xa[col * 36 + (c0 >> 1)]     = packbf2(d[0], d[1]);
                    xa[col * 36 + (c0 >> 1) + 1] = packbf2(d[2], d[3]);
                }
            }
        }
        __syncthreads();
        // ---- main GEMM: acc[o,col] += gw_i[o,c] * xa[c,col]
        #pragma unroll
        for (int ct = 0; ct < 8; ++ct) {
            #pragma unroll
            for (int s = 0; s < 2; ++s) {
                short8 bfrag = *(const short8*)((const ushort16*)xa +
                                                (ct * 16 + l15) * 72 + s * 32 + q * 8);
                acc[ct] = __builtin_amdgcn_mfma_f32_16x16x32_bf16(
                    gf[i * 2 + s], bfrag, acc[ct], 0, 0, 0);
            }
        }
    }

    // ---- epilogue: BN + residual (bf16 xs) + relu, direct coalesced store
    const int o0 = w * 16 + q * 4;
    #pragma unroll
    for (int ct = 0; ct < 8; ++ct) {
        int col = ct * 16 + l15;
        if (col < 125) {
            int tl = col / 25;
            int v  = col - tl * 25;
            float* ob = out + (n * 64 + o0) * 7500 + t0 * 25 + col;
            #pragma unroll
            for (int r = 0; r < 4; ++r) {
                int o = o0 + r;
                float xv = bf2f(xs[o * 168 + tl * 32 + v]);
                float h = acc[ct][r] * bsc[o] + bsh[o] + xv;
                ob[r * 7500] = fmaxf(h, 0.f);
            }
        }
    }
}

// ---------------------------------------------------------------- launch
extern "C" void kernel_launch(void* const* d_in, const int* in_sizes, int n_in,
                              void* d_out, int out_size, void* d_ws, size_t ws_size,
                              hipStream_t stream) {
    const float* x    = (const float*)d_in[0];
    const float* A    = (const float*)d_in[1];
    const float* GA   = (const float*)d_in[2];
    const float* g_w  = (const float*)d_in[3];
    const float* g_b  = (const float*)d_in[4];
    const float* a_w  = (const float*)d_in[5];
    const float* a_b  = (const float*)d_in[6];
    const float* b_w  = (const float*)d_in[7];
    const float* b_b  = (const float*)d_in[8];
    const float* bn_g = (const float*)d_in[9];
    const float* bn_b = (const float*)d_in[10];
    const float* bn_m = (const float*)d_in[11];
    const float* bn_v = (const float*)d_in[12];
    float* out = (float*)d_out;

    // ws: Mb f32[120000] (480000 B) | atT bf16 (393216 B) | gwb (24576 B)
    // wb2 (12288 B) OVERLAPS the start of atT: k0 writes wb2 -> k1 reads
    // wb2 -> k2 overwrites region with atT -> k3 reads atT. Stream-serial.
    float*    Mb  = (float*)d_ws;
    uint32*   atT = (uint32*)((char*)d_ws + 480000);
    ushort16* wb2 = (ushort16*)((char*)d_ws + 480000);
    uint32*   gwb = (uint32*)((char*)d_ws + 480000 + 393216);

    hipMemsetAsync(d_ws, 0, 480000, stream);  // zero M accumulators
    k0_prep<<<dim3(48), dim3(256), 0, stream>>>(a_w, b_w, g_w, wb2, gwb);
    k1_attn_logits_mfma<<<dim3(1600), dim3(256), 0, stream>>>(x, wb2, a_b, b_b, Mb);
    k2_softmax<<<dim3(192), dim3(128), 0, stream>>>(Mb, A, GA, atT);
    k3_out<<<dim3(3840), dim3(256), 0, stream>>>(x, atT, (const ushort16*)gwb,
                                                 g_b, bn_g, bn_b, bn_m, bn_v, out);
}

// Round 5
// 356.259 us; speedup vs baseline: 1.1759x; 1.1759x over previous
//
#include <hip/hip_runtime.h>
#include <hip/hip_bf16.h>

// AdaptiveGraphConvolution on MI355X — round 7.
// N=64, C=64, T=300, V=25, S=3 subsets, IC=16, O=64.
//
// Round-6 post-mortem: amdgpu_waves_per_eu(4,4) did NOT raise the VGPR
// budget (VGPR_Count stayed 64) and spill traffic grew (FETCH 214 MB,
// WRITE 133 MB, k1 153 us). Two rounds of evidence: the allocator pins
// this kernel at 64 VGPRs; design for <=64.
// Round-7 fix (k1 only): remove the cross-phase pf[7] prefetch (28 VGPRs
// live across the MFMA phases = the spill source). Staging is now a
// self-contained phase: 7 independent load+cvt+LDS-write per thread
// (ILP hides HBM latency within the phase; TLP across 16 waves/CU hides
// the rest). Peak pressure = max(staging ~50, compute ~55) < 64.
// Kept from rounds 5/6 (correctness proven twice): k0 weight prep, W
// from global wb2, bias stash in abT rows 31/63/95, 32x32x16 phase A,
// LDS 40.7 KB = 4 blocks/CU, native f2bf, direct-from-AGPR atomics.
// k0/k2/k3 unchanged.

#define NB 64
#define CB 64
#define TB 300
#define VB 25

typedef unsigned int uint32;
typedef unsigned short ushort16;
typedef __attribute__((ext_vector_type(8))) short short8;
typedef __attribute__((ext_vector_type(4))) float f32x4;
typedef __attribute__((ext_vector_type(16))) float f32x16;

__device__ __forceinline__ ushort16 f2bf(float f) {
    __hip_bfloat16 h = __float2bfloat16(f);
    ushort16 u;
    __builtin_memcpy(&u, &h, sizeof(u));
    return u;
}
__device__ __forceinline__ float bf2f(ushort16 h) {
    return __uint_as_float(((uint32)h) << 16);
}
__device__ __forceinline__ uint32 packbf2(float a, float b) {
    return (uint32)f2bf(a) | ((uint32)f2bf(b) << 16);
}

// ---------------------------------------------------------------- kernel 0
// one-time weight prep. grid 48 x 256.
//   idx <  6144: W bf16, layout [kb8][r][8]:  wb2[(kb*96+r)*8+ci] = W[r][kb*8+ci]
//   idx < 12288: g_w -> gwb bf16 pairs (k3 A-operand layout)
__global__ __launch_bounds__(256) void k0_prep(
    const float* __restrict__ a_w, const float* __restrict__ b_w,
    const float* __restrict__ g_w,
    ushort16* __restrict__ wb2, uint32* __restrict__ gwb)
{
    int idx = blockIdx.x * 256 + threadIdx.x;
    if (idx < 6144) {
        int kb = idx / 768, rem = idx % 768;
        int r = rem >> 3, ci = rem & 7;
        int c = kb * 8 + ci;
        float v = (r < 48) ? a_w[r * 64 + c] : b_w[(r - 48) * 64 + c];
        wb2[idx] = f2bf(v);
    } else if (idx < 12288) {
        int j = idx - 6144;
        int o = j / 96, kp = j % 96;
        int k0 = 2 * kp, i = k0 >> 6, c = k0 & 63;
        float2 lh = *(const float2*)(g_w + (i * 64 + o) * 64 + c);
        gwb[j] = packbf2(lh.x, lh.y);
    }
}

// ---------------------------------------------------------------- kernel 1
// grid 1600 = 64 n * 25 chunks (12 t), 256 thr = 4 waves, 4 blocks/CU
__global__ __launch_bounds__(256) void k1_attn_logits_mfma(
    const float* __restrict__ x, const ushort16* __restrict__ wb2,
    const float* __restrict__ a_b, const float* __restrict__ b_b,
    float* __restrict__ Mb)
{
    // pool: xT[126 rows][64] (rows >=100 read-only garbage, reads for
    // tv 126/127 spill into abT rows 0/1 -> discarded cols), then
    // abT[192 rows][64]. Total 40704 B -> 4 blocks/CU.
    __shared__ ushort16 pool[20352];
    ushort16* xT  = pool;
    ushort16* abT = pool + 126 * 64;

    const int tid   = threadIdx.x;
    const int n     = blockIdx.x / 25;
    const int chunk = blockIdx.x % 25;
    const float* xn = x + n * (CB * TB * VB);

    // bias stash: f32 in abT rows 31/63/95 (phase-B reads of rows v>=25
    // produce discarded outputs; phase-A writes only touch v<25).
    if (tid < 96) {
        float v = (tid < 48) ? a_b[tid] : b_b[tid - 48];
        ((float*)(abT + (31 + (tid >> 5) * 32) * 64))[tid & 31] = v;
    }

    const int w    = tid >> 6;
    const int lane = tid & 63;
    const int hi   = lane >> 5;
    const int v32  = lane & 31;

    const float* xb0 = xn + chunk * 12 * 25;

    // phase-A hoists: wave w owns col-tile ct=w
    const int tv     = w * 32 + v32;
    const bool avalid = tv < 100;
    const int tl = tv / 25;
    const int vv = tv - tl * 25;

    f32x16 accB;
    #pragma unroll
    for (int r = 0; r < 16; ++r) accB[r] = 0.f;

    for (int s = 0; s < 3; ++s) {
        __syncthreads();   // phase A/B of s-1 done with xT/abT
        // ---- stage x^T sub-chunk: load + cvt + swizzled LDS write.
        // row tv = 4j+e, swizzle block = ((c>>3) + tv + (tv>>2)) & 7
        //   = ((c>>3) + 5j + e) & 7  since (4j+e)>>2 == j for e<4.
        // All 7 loads are independent -> issued back-to-back (ILP covers
        // HBM latency within the phase); no cross-phase register liveness.
        const float* xs0 = xb0 + s * 100;
        #pragma unroll
        for (int k = 0; k < 7; ++k) {
            int idx = tid + k * 256;
            if (idx < 1600) {
                int c = idx / 25, j = idx - c * 25;
                float4 v4 = *(const float4*)(xs0 + c * 7500 + j * 4);
                int sb   = ((c >> 3) + 5 * j) & 7;
                int base = (4 * j) * 64 + (c & 7);
                xT[base +   0 + (((sb + 0) & 7) << 3)] = f2bf(v4.x);
                xT[base +  64 + (((sb + 1) & 7) << 3)] = f2bf(v4.y);
                xT[base + 128 + (((sb + 2) & 7) << 3)] = f2bf(v4.z);
                xT[base + 192 + (((sb + 3) & 7) << 3)] = f2bf(v4.w);
            }
        }
        __syncthreads();
        // ---- phase A: ab = W @ x on 32x32x16; 3 rt tiles, ct = w
        #pragma unroll
        for (int rt = 0; rt < 3; ++rt) {
            f32x16 d;
            #pragma unroll
            for (int r = 0; r < 16; ++r) d[r] = 0.f;
            #pragma unroll
            for (int k16 = 0; k16 < 4; ++k16) {
                int kb = k16 * 2 + hi;
                short8 af = *(const short8*)(wb2 + (kb * 96 + rt * 32 + v32) * 8);
                short8 bf = *(const short8*)&xT[tv * 64 +
                                                (((kb + tv + (tv >> 2)) & 7) << 3)];
                d = __builtin_amdgcn_mfma_f32_32x32x16_bf16(af, bf, d, 0, 0, 0);
            }
            if (avalid) {
                #pragma unroll
                for (int a = 0; a < 4; ++a) {
                    int rowoff = 8 * a + 4 * hi;            // D row within 32
                    int g   = rt * 2 + (rowoff >> 4);       // abT group
                    int icb = rowoff & 15;
                    float4 bq = *(const float4*)(
                        (const float*)(abT + (31 + rt * 32) * 64) + rowoff);
                    int kbw = tl * 2 + (icb >> 3);
                    uint32* dst = (uint32*)&abT[(g * 32 + vv) * 64 +
                                                (((kbw + vv) & 7) << 3) + (icb & 7)];
                    dst[0] = packbf2(d[4 * a + 0] + bq.x, d[4 * a + 1] + bq.y);
                    dst[1] = packbf2(d[4 * a + 2] + bq.z, d[4 * a + 3] + bq.w);
                }
            }
        }
        __syncthreads();
        // ---- phase B: wave w (<3) owns subset i=w, all 4 local t
        if (w < 3) {
            #pragma unroll
            for (int tl2 = 0; tl2 < 4; ++tl2) {
                int kb = tl2 * 2 + hi;
                short8 af = *(const short8*)&abT[(w * 32 + v32) * 64 +
                                                 (((kb + v32) & 7) << 3)];
                short8 bf = *(const short8*)&abT[((3 + w) * 32 + v32) * 64 +
                                                 (((kb + v32) & 7) << 3)];
                accB = __builtin_amdgcn_mfma_f32_32x32x16_bf16(af, bf, accB, 0, 0, 0);
            }
        }
    }

    // ---- tail: each wave holds a full M_i -> atomics straight from regs
    if (w < 3 && v32 < 25) {
        const float inv = 1.0f / 4800.0f;
        #pragma unroll
        for (int r = 0; r < 16; ++r) {
            int row = (r & 3) + 8 * (r >> 2) + 4 * hi;   // m74/m101 C-layout
            if (row < 25)
                atomicAdd(Mb + ((w * NB + n) * 25 + row) * 25 + v32, accB[r] * inv);
        }
    }
}

// ---------------------------------------------------------------- kernel 2
// 192 blocks = (i,n); softmax over v1 + A_tot -> atT bf16 [i][n][v2][v1 pad32]
__global__ __launch_bounds__(128) void k2_softmax(
    const float* __restrict__ Mb, const float* __restrict__ A,
    const float* __restrict__ GA, uint32* __restrict__ atT)
{
    __shared__ float Ms[640];
    const int b   = blockIdx.x;
    const int tid = threadIdx.x;
    const int i = b >> 6, n = b & 63;
    const float* src = Mb + b * 625;       // [i][n] tile, contiguous
    for (int idx = tid; idx < 625; idx += 128) Ms[idx] = src[idx];
    __syncthreads();
    if (tid < 25) {
        const int v2 = tid;
        float e[25], mx = -1e30f;
        #pragma unroll
        for (int v1 = 0; v1 < 25; ++v1) {
            e[v1] = Ms[v1 * 25 + v2];
            mx = fmaxf(mx, e[v1]);
        }
        float s = 0.f;
        #pragma unroll
        for (int v1 = 0; v1 < 25; ++v1) { e[v1] = __expf(e[v1] - mx); s += e[v1]; }
        float invs = 1.0f / s;
        const float* acol = A + i * 625 + v2;
        const float* gcol = GA + i * 625 + v2;
        float wv[25];
        #pragma unroll
        for (int v1 = 0; v1 < 25; ++v1)
            wv[v1] = e[v1] * invs + acol[v1 * 25] + gcol[v1 * 25];
        uint32* row = atT + ((i * 64 + n) * 32 + v2) * 16;
        #pragma unroll
        for (int p = 0; p < 12; ++p) row[p] = packbf2(wv[2 * p], wv[2 * p + 1]);
        row[12] = (uint32)f2bf(wv[24]);
        row[13] = 0u; row[14] = 0u; row[15] = 0u;
    }
}

// ---------------------------------------------------------------- kernel 3
// MFMA. grid 3840 = 64 n * 60 chunks of 5 t; 256 thr = 4 waves (wave=o/c tile)
__global__ __launch_bounds__(256) void k3_out(
    const float* __restrict__ x, const uint32* __restrict__ atT,
    const ushort16* __restrict__ gwb, const float* __restrict__ g_b,
    const float* __restrict__ bn_g, const float* __restrict__ bn_b,
    const float* __restrict__ bn_m, const float* __restrict__ bn_v,
    float* __restrict__ out)
{
    __shared__ ushort16 xs[64 * 168];   // [c][t*32 + v1]  (stride 168: 2-way banks)
    __shared__ uint32  xa[128 * 36];    // [col=(t,v2) pad128][c: 72 bf16 as 36 u32]
    __shared__ uint32  ats[3 * 32 * 20];// [i][v2][v1: 40 bf16 as 20 u32]
    __shared__ float   bsc[64], bsh[64];

    const int tid = threadIdx.x;
    const int n  = blockIdx.x / 60;
    const int t0 = (blockIdx.x % 60) * 5;

    // stage x tile -> bf16 [c][t][v1]
    for (int idx = tid; idx < 8000; idx += 256) {
        int c = idx / 125, tv = idx % 125;
        int t = tv / 25, v = tv % 25;
        float g = x[((n * 64 + c) * 300 + t0 + t) * 25 + v];
        xs[c * 168 + t * 32 + v] = f2bf(g);
    }
    for (int idx = tid; idx < 64 * 35; idx += 256) {   // zero v1 in [25,32)
        int c = idx / 35, r = idx % 35;
        xs[c * 168 + (r / 7) * 32 + 25 + (r % 7)] = (ushort16)0;
    }
    // stage attn^T rows for this n
    for (int idx = tid; idx < 1536; idx += 256) {
        int row = idx >> 4, d = idx & 15;   // row = i*32+v2
        ats[row * 20 + d] = atT[((row >> 5) * 64 + n) * 512 + (row & 31) * 16 + d];
    }
    // BN scale/shift prefold (h = acc*sc + sh + x)
    for (int idx = tid; idx < 64; idx += 256) {
        float sc = bn_g[idx] * rsqrtf(bn_v[idx] + 1e-5f);
        bsc[idx] = sc;
        bsh[idx] = (g_b[idx] + g_b[64 + idx] + g_b[128 + idx] - bn_m[idx]) * sc + bn_b[idx];
    }
    // zero xa pad rows (cols 125..127)
    for (int idx = tid; idx < 3 * 36; idx += 256)
        xa[(125 + idx / 36) * 36 + idx % 36] = 0u;

    const int w    = tid >> 6;      // wave id = o-tile (main) = c-tile (xa)
    const int lane = tid & 63;
    const int l15  = lane & 15;
    const int q    = lane >> 4;

    // preload A-frags of gw (all 6 K-steps: k = i*64 + s*32)
    short8 gf[6];
    #pragma unroll
    for (int s = 0; s < 6; ++s)
        gf[s] = *(const short8*)(gwb + ((w * 16 + l15) * 192 + s * 32 + q * 8));

    f32x4 acc[8];
    #pragma unroll
    for (int ct = 0; ct < 8; ++ct) acc[ct] = (f32x4){0.f, 0.f, 0.f, 0.f};
    const f32x4 zf = (f32x4){0.f, 0.f, 0.f, 0.f};

    __syncthreads();

    for (int i = 0; i < 3; ++i) {
        if (i) __syncthreads();   // previous xa fully consumed
        // ---- xa-phase: this wave produces c-rows [w*16, w*16+16)
        #pragma unroll
        for (int t = 0; t < 5; ++t) {
            short8 ax = *(const short8*)(xs + (w * 16 + l15) * 168 + t * 32 + q * 8);
            #pragma unroll
            for (int vt = 0; vt < 2; ++vt) {
                short8 bt = *(const short8*)((const ushort16*)ats +
                                             (i * 32 + vt * 16 + l15) * 40 + q * 8);
                f32x4 d = __builtin_amdgcn_mfma_f32_16x16x32_bf16(ax, bt, zf, 0, 0, 0);
                int v2 = vt * 16 + l15;
                if (v2 < 25) {
                    int col = t * 25 + v2;
                    int c0  = w * 16 + q * 4;
                    xa[col * 36 + (c0 >> 1)]     = packbf2(d[0], d[1]);
                    xa[col * 36 + (c0 >> 1) + 1] = packbf2(d[2], d[3]);
                }
            }
        }
        __syncthreads();
        // ---- main GEMM: acc[o,col] += gw_i[o,c] * xa[c,col]
        #pragma unroll
        for (int ct = 0; ct < 8; ++ct) {
            #pragma unroll
            for (int s = 0; s < 2; ++s) {
                short8 bfrag = *(const short8*)((const ushort16*)xa +
                                                (ct * 16 + l15) * 72 + s * 32 + q * 8);
                acc[ct] = __builtin_amdgcn_mfma_f32_16x16x32_bf16(
                    gf[i * 2 + s], bfrag, acc[ct], 0, 0, 0);
            }
        }
    }

    // ---- epilogue: BN + residual (bf16 xs) + relu, direct coalesced store
    const int o0 = w * 16 + q * 4;
    #pragma unroll
    for (int ct = 0; ct < 8; ++ct) {
        int col = ct * 16 + l15;
        if (col < 125) {
            int tl = col / 25;
            int v  = col - tl * 25;
            float* ob = out + (n * 64 + o0) * 7500 + t0 * 25 + col;
            #pragma unroll
            for (int r = 0; r < 4; ++r) {
                int o = o0 + r;
                float xv = bf2f(xs[o * 168 + tl * 32 + v]);
                float h = acc[ct][r] * bsc[o] + bsh[o] + xv;
                ob[r * 7500] = fmaxf(h, 0.f);
            }
        }
    }
}

// ---------------------------------------------------------------- launch
extern "C" void kernel_launch(void* const* d_in, const int* in_sizes, int n_in,
                              void* d_out, int out_size, void* d_ws, size_t ws_size,
                              hipStream_t stream) {
    const float* x    = (const float*)d_in[0];
    const float* A    = (const float*)d_in[1];
    const float* GA   = (const float*)d_in[2];
    const float* g_w  = (const float*)d_in[3];
    const float* g_b  = (const float*)d_in[4];
    const float* a_w  = (const float*)d_in[5];
    const float* a_b  = (const float*)d_in[6];
    const float* b_w  = (const float*)d_in[7];
    const float* b_b  = (const float*)d_in[8];
    const float* bn_g = (const float*)d_in[9];
    const float* bn_b = (const float*)d_in[10];
    const float* bn_m = (const float*)d_in[11];
    const float* bn_v = (const float*)d_in[12];
    float* out = (float*)d_out;

    // ws: Mb f32[120000] (480000 B) | atT bf16 (393216 B) | gwb (24576 B)
    // wb2 (12288 B) OVERLAPS the start of atT: k0 writes wb2 -> k1 reads
    // wb2 -> k2 overwrites region with atT -> k3 reads atT. Stream-serial.
    float*    Mb  = (float*)d_ws;
    uint32*   atT = (uint32*)((char*)d_ws + 480000);
    ushort16* wb2 = (ushort16*)((char*)d_ws + 480000);
    uint32*   gwb = (uint32*)((char*)d_ws + 480000 + 393216);

    hipMemsetAsync(d_ws, 0, 480000, stream);  // zero M accumulators
    k0_prep<<<dim3(48), dim3(256), 0, stream>>>(a_w, b_w, g_w, wb2, gwb);
    k1_attn_logits_mfma<<<dim3(1600), dim3(256), 0, stream>>>(x, wb2, a_b, b_b, Mb);
    k2_softmax<<<dim3(192), dim3(128), 0, stream>>>(Mb, A, GA, atT);
    k3_out<<<dim3(3840), dim3(256), 0, stream>>>(x, atT, (const ushort16*)gwb,
                                                 g_b, bn_g, bn_b, bn_m, bn_v, out);
}

// Round 6
// 343.304 us; speedup vs baseline: 1.2202x; 1.0377x over previous
//
#include <hip/hip_runtime.h>
#include <hip/hip_bf16.h>

// AdaptiveGraphConvolution on MI355X — round 8.
// N=64, C=64, T=300, V=25, S=3 subsets, IC=16, O=64.
//
// Round-7 post-mortem: k1 fixed (dropped out of top-5, ~85 us). k3 is now
// the top dispatch (88 us) and is VALU-instruction-bound: VALUBusy 49%
// (~43 us = ~900 VALU inst/thread, half of it the x->LDS staging pass
// with per-element div-by-125/25 + f2bf), MfmaUtil 9%, HBM 30%.
// Round-8 (k3 rewrite, stage-less):
//  * xs LDS buffer + 8000-element staging pass DELETED. xa-phase A-frags
//    are built directly in registers from global x: lane (q,l15) of wave
//    w loads x[n][w*16+l15][t0+t][q*8..+8) as 8 scalar floats + 4 cvt
//    packs, hoisted over the i-loop (i-invariant, axf[5] = 20 VGPR).
//    v1>=25 elements are garbage-not-zero: safe because atT's B operand
//    is zero there (k2 pads rows 25..31 with 0) and the garbage is
//    clamped in-bounds finite x data, so garbage*0 = 0.
//  * ats LDS bounce deleted: B-frags (atT rows, 16B-aligned) are read
//    straight from global per i (L2-hot, 2 dwordx4 per i per lane).
//  * epilogue residual reads x f32 from global at the same offsets as
//    the out stores (no div, L2-hot) instead of bf16 from LDS.
//  * LDS 48128 -> 18944 B (xa + bsc/bsh only).
//  * k0 also zeroes Mb (hipMemsetAsync dispatch removed).
// k1/k2 unchanged from round 7.

#define NB 64
#define CB 64
#define TB 300
#define VB 25
#define XTOT (NB * CB * TB * VB)

typedef unsigned int uint32;
typedef unsigned short ushort16;
typedef __attribute__((ext_vector_type(8))) short short8;
typedef __attribute__((ext_vector_type(4))) float f32x4;
typedef __attribute__((ext_vector_type(16))) float f32x16;

__device__ __forceinline__ ushort16 f2bf(float f) {
    __hip_bfloat16 h = __float2bfloat16(f);
    ushort16 u;
    __builtin_memcpy(&u, &h, sizeof(u));
    return u;
}
__device__ __forceinline__ float bf2f(ushort16 h) {
    return __uint_as_float(((uint32)h) << 16);
}
__device__ __forceinline__ uint32 packbf2(float a, float b) {
    return (uint32)f2bf(a) | ((uint32)f2bf(b) << 16);
}

// ---------------------------------------------------------------- kernel 0
// one-time prep. grid 48 x 256.
//   - zero Mb accumulators (replaces hipMemsetAsync dispatch)
//   - idx <  6144: W bf16, layout [kb8][r][8]
//   - idx < 12288: g_w -> gwb bf16 pairs (k3 A-operand layout)
__global__ __launch_bounds__(256) void k0_prep(
    const float* __restrict__ a_w, const float* __restrict__ b_w,
    const float* __restrict__ g_w,
    ushort16* __restrict__ wb2, uint32* __restrict__ gwb,
    float* __restrict__ Mb)
{
    int idx = blockIdx.x * 256 + threadIdx.x;
    for (int z = idx; z < 120000; z += 12288) Mb[z] = 0.f;
    if (idx < 6144) {
        int kb = idx / 768, rem = idx % 768;
        int r = rem >> 3, ci = rem & 7;
        int c = kb * 8 + ci;
        float v = (r < 48) ? a_w[r * 64 + c] : b_w[(r - 48) * 64 + c];
        wb2[idx] = f2bf(v);
    } else if (idx < 12288) {
        int j = idx - 6144;
        int o = j / 96, kp = j % 96;
        int k0 = 2 * kp, i = k0 >> 6, c = k0 & 63;
        float2 lh = *(const float2*)(g_w + (i * 64 + o) * 64 + c);
        gwb[j] = packbf2(lh.x, lh.y);
    }
}

// ---------------------------------------------------------------- kernel 1
// grid 1600 = 64 n * 25 chunks (12 t), 256 thr = 4 waves, 4 blocks/CU
__global__ __launch_bounds__(256) void k1_attn_logits_mfma(
    const float* __restrict__ x, const ushort16* __restrict__ wb2,
    const float* __restrict__ a_b, const float* __restrict__ b_b,
    float* __restrict__ Mb)
{
    // pool: xT[126 rows][64] + abT[192 rows][64]. 40704 B -> 4 blocks/CU.
    __shared__ ushort16 pool[20352];
    ushort16* xT  = pool;
    ushort16* abT = pool + 126 * 64;

    const int tid   = threadIdx.x;
    const int n     = blockIdx.x / 25;
    const int chunk = blockIdx.x % 25;
    const float* xn = x + n * (CB * TB * VB);

    // bias stash: f32 in abT rows 31/63/95 (phase-B reads of rows v>=25
    // produce discarded outputs; phase-A writes only touch v<25).
    if (tid < 96) {
        float v = (tid < 48) ? a_b[tid] : b_b[tid - 48];
        ((float*)(abT + (31 + (tid >> 5) * 32) * 64))[tid & 31] = v;
    }

    const int w    = tid >> 6;
    const int lane = tid & 63;
    const int hi   = lane >> 5;
    const int v32  = lane & 31;

    const float* xb0 = xn + chunk * 12 * 25;

    // phase-A hoists: wave w owns col-tile ct=w
    const int tv     = w * 32 + v32;
    const bool avalid = tv < 100;
    const int tl = tv / 25;
    const int vv = tv - tl * 25;

    f32x16 accB;
    #pragma unroll
    for (int r = 0; r < 16; ++r) accB[r] = 0.f;

    for (int s = 0; s < 3; ++s) {
        __syncthreads();   // phase A/B of s-1 done with xT/abT
        // ---- stage x^T sub-chunk: load + cvt + swizzled LDS write.
        // row tv = 4j+e, swizzle block = ((c>>3) + 5j + e) & 7.
        const float* xs0 = xb0 + s * 100;
        #pragma unroll
        for (int k = 0; k < 7; ++k) {
            int idx = tid + k * 256;
            if (idx < 1600) {
                int c = idx / 25, j = idx - c * 25;
                float4 v4 = *(const float4*)(xs0 + c * 7500 + j * 4);
                int sb   = ((c >> 3) + 5 * j) & 7;
                int base = (4 * j) * 64 + (c & 7);
                xT[base +   0 + (((sb + 0) & 7) << 3)] = f2bf(v4.x);
                xT[base +  64 + (((sb + 1) & 7) << 3)] = f2bf(v4.y);
                xT[base + 128 + (((sb + 2) & 7) << 3)] = f2bf(v4.z);
                xT[base + 192 + (((sb + 3) & 7) << 3)] = f2bf(v4.w);
            }
        }
        __syncthreads();
        // ---- phase A: ab = W @ x on 32x32x16; 3 rt tiles, ct = w
        #pragma unroll
        for (int rt = 0; rt < 3; ++rt) {
            f32x16 d;
            #pragma unroll
            for (int r = 0; r < 16; ++r) d[r] = 0.f;
            #pragma unroll
            for (int k16 = 0; k16 < 4; ++k16) {
                int kb = k16 * 2 + hi;
                short8 af = *(const short8*)(wb2 + (kb * 96 + rt * 32 + v32) * 8);
                short8 bf = *(const short8*)&xT[tv * 64 +
                                                (((kb + tv + (tv >> 2)) & 7) << 3)];
                d = __builtin_amdgcn_mfma_f32_32x32x16_bf16(af, bf, d, 0, 0, 0);
            }
            if (avalid) {
                #pragma unroll
                for (int a = 0; a < 4; ++a) {
                    int rowoff = 8 * a + 4 * hi;            // D row within 32
                    int g   = rt * 2 + (rowoff >> 4);       // abT group
                    int icb = rowoff & 15;
                    float4 bq = *(const float4*)(
                        (const float*)(abT + (31 + rt * 32) * 64) + rowoff);
                    int kbw = tl * 2 + (icb >> 3);
                    uint32* dst = (uint32*)&abT[(g * 32 + vv) * 64 +
                                                (((kbw + vv) & 7) << 3) + (icb & 7)];
                    dst[0] = packbf2(d[4 * a + 0] + bq.x, d[4 * a + 1] + bq.y);
                    dst[1] = packbf2(d[4 * a + 2] + bq.z, d[4 * a + 3] + bq.w);
                }
            }
        }
        __syncthreads();
        // ---- phase B: wave w (<3) owns subset i=w, all 4 local t
        if (w < 3) {
            #pragma unroll
            for (int tl2 = 0; tl2 < 4; ++tl2) {
                int kb = tl2 * 2 + hi;
                short8 af = *(const short8*)&abT[(w * 32 + v32) * 64 +
                                                 (((kb + v32) & 7) << 3)];
                short8 bf = *(const short8*)&abT[((3 + w) * 32 + v32) * 64 +
                                                 (((kb + v32) & 7) << 3)];
                accB = __builtin_amdgcn_mfma_f32_32x32x16_bf16(af, bf, accB, 0, 0, 0);
            }
        }
    }

    // ---- tail: each wave holds a full M_i -> atomics straight from regs
    if (w < 3 && v32 < 25) {
        const float inv = 1.0f / 4800.0f;
        #pragma unroll
        for (int r = 0; r < 16; ++r) {
            int row = (r & 3) + 8 * (r >> 2) + 4 * hi;   // m74/m101 C-layout
            if (row < 25)
                atomicAdd(Mb + ((w * NB + n) * 25 + row) * 25 + v32, accB[r] * inv);
        }
    }
}

// ---------------------------------------------------------------- kernel 2
// 192 blocks = (i,n); softmax over v1 + A_tot -> atT bf16 [i][n][v2][v1 pad32]
__global__ __launch_bounds__(128) void k2_softmax(
    const float* __restrict__ Mb, const float* __restrict__ A,
    const float* __restrict__ GA, uint32* __restrict__ atT)
{
    __shared__ float Ms[640];
    const int b   = blockIdx.x;
    const int tid = threadIdx.x;
    const int i = b >> 6, n = b & 63;
    const float* src = Mb + b * 625;       // [i][n] tile, contiguous
    for (int idx = tid; idx < 625; idx += 128) Ms[idx] = src[idx];
    __syncthreads();
    if (tid < 25) {
        const int v2 = tid;
        float e[25], mx = -1e30f;
        #pragma unroll
        for (int v1 = 0; v1 < 25; ++v1) {
            e[v1] = Ms[v1 * 25 + v2];
            mx = fmaxf(mx, e[v1]);
        }
        float s = 0.f;
        #pragma unroll
        for (int v1 = 0; v1 < 25; ++v1) { e[v1] = __expf(e[v1] - mx); s += e[v1]; }
        float invs = 1.0f / s;
        const float* acol = A + i * 625 + v2;
        const float* gcol = GA + i * 625 + v2;
        float wv[25];
        #pragma unroll
        for (int v1 = 0; v1 < 25; ++v1)
            wv[v1] = e[v1] * invs + acol[v1 * 25] + gcol[v1 * 25];
        uint32* row = atT + ((i * 64 + n) * 32 + v2) * 16;
        #pragma unroll
        for (int p = 0; p < 12; ++p) row[p] = packbf2(wv[2 * p], wv[2 * p + 1]);
        row[12] = (uint32)f2bf(wv[24]);
        row[13] = 0u; row[14] = 0u; row[15] = 0u;
    }
}

// ---------------------------------------------------------------- kernel 3
// Stage-less MFMA. grid 3840 = 64 n * 60 chunks of 5 t; 256 thr = 4 waves.
// LDS: xa 18432 + bsc/bsh 512 = 18944 B.
__global__ __launch_bounds__(256) void k3_out(
    const float* __restrict__ x, const uint32* __restrict__ atT,
    const ushort16* __restrict__ gwb, const float* __restrict__ g_b,
    const float* __restrict__ bn_g, const float* __restrict__ bn_b,
    const float* __restrict__ bn_m, const float* __restrict__ bn_v,
    float* __restrict__ out)
{
    __shared__ uint32 xa[128 * 36];     // [col=(t,v2) pad128][c: 72 bf16 as 36 u32]
    __shared__ float  bsc[64], bsh[64];

    const int tid = threadIdx.x;
    const int n  = blockIdx.x / 60;
    const int t0 = (blockIdx.x % 60) * 5;

    // BN scale/shift prefold (h = acc*sc + sh + x)
    if (tid < 64) {
        float sc = bn_g[tid] * rsqrtf(bn_v[tid] + 1e-5f);
        bsc[tid] = sc;
        bsh[tid] = (g_b[tid] + g_b[64 + tid] + g_b[128 + tid] - bn_m[tid]) * sc
                   + bn_b[tid];
    }
    // zero xa pad rows (cols 125..127)
    for (int idx = tid; idx < 108; idx += 256)
        xa[(125 + idx / 36) * 36 + idx % 36] = 0u;

    const int w    = tid >> 6;      // wave id = o-tile (main) = c-tile (xa)
    const int lane = tid & 63;
    const int l15  = lane & 15;
    const int q    = lane >> 4;

    // preload A-frags of gw (all 6 K-steps: k = i*64 + s*32)
    short8 gf[6];
    #pragma unroll
    for (int s = 0; s < 6; ++s)
        gf[s] = *(const short8*)(gwb + ((w * 16 + l15) * 192 + s * 32 + q * 8));

    // A-frags of x direct from global: lane (q,l15) of wave w holds
    // c = w*16+l15, k = v1 in [q*8, q*8+8). v1 >= 25 reads the next t-row
    // (garbage but finite, in-bounds via clamp) and meets B's zero pad.
    const int c    = w * 16 + l15;
    const int rowf = (n * 64 + c) * 7500 + t0 * 25;
    short8 axf[5];
    #pragma unroll
    for (int t = 0; t < 5; ++t) {
        int fi = rowf + t * 25 + q * 8;
        fi = fi < (XTOT - 8) ? fi : (XTOT - 8);
        const float* p = x + fi;
        union { short8 s; uint32 u[4]; } fr;
        fr.u[0] = packbf2(p[0], p[1]);
        fr.u[1] = packbf2(p[2], p[3]);
        fr.u[2] = packbf2(p[4], p[5]);
        fr.u[3] = packbf2(p[6], p[7]);
        axf[t] = fr.s;
    }

    f32x4 acc[8];
    #pragma unroll
    for (int ct = 0; ct < 8; ++ct) acc[ct] = (f32x4){0.f, 0.f, 0.f, 0.f};
    const f32x4 zf = (f32x4){0.f, 0.f, 0.f, 0.f};

    __syncthreads();

    for (int i = 0; i < 3; ++i) {
        if (i) __syncthreads();   // previous xa fully consumed
        // B-frags for this i straight from global atT (16B-aligned, L2-hot)
        const ushort16* ap = (const ushort16*)atT + ((i * 64 + n) * 32) * 32;
        short8 bt0 = *(const short8*)(ap + l15 * 32 + q * 8);
        short8 bt1 = *(const short8*)(ap + (16 + l15) * 32 + q * 8);
        // ---- xa-phase: this wave produces c-rows [w*16, w*16+16)
        #pragma unroll
        for (int t = 0; t < 5; ++t) {
            #pragma unroll
            for (int vt = 0; vt < 2; ++vt) {
                f32x4 d = __builtin_amdgcn_mfma_f32_16x16x32_bf16(
                    axf[t], vt ? bt1 : bt0, zf, 0, 0, 0);
                int v2 = vt * 16 + l15;
                if (v2 < 25) {
                    int col = t * 25 + v2;
                    int c0  = w * 16 + q * 4;
                    xa[col * 36 + (c0 >> 1)]     = packbf2(d[0], d[1]);
                    xa[col * 36 + (c0 >> 1) + 1] = packbf2(d[2], d[3]);
                }
            }
        }
        __syncthreads();
        // ---- main GEMM: acc[o,col] += gw_i[o,c] * xa[c,col]
        #pragma unroll
        for (int ct = 0; ct < 8; ++ct) {
            #pragma unroll
            for (int s = 0; s < 2; ++s) {
                short8 bfrag = *(const short8*)((const ushort16*)xa +
                                                (ct * 16 + l15) * 72 + s * 32 + q * 8);
                acc[ct] = __builtin_amdgcn_mfma_f32_16x16x32_bf16(
                    gf[i * 2 + s], bfrag, acc[ct], 0, 0, 0);
            }
        }
    }

    // ---- epilogue: BN + residual (f32 x from global, same offsets as out)
    const int o0 = w * 16 + q * 4;
    #pragma unroll
    for (int ct = 0; ct < 8; ++ct) {
        int col = ct * 16 + l15;
        if (col < 125) {
            int off = (n * 64 + o0) * 7500 + t0 * 25 + col;
            float* ob = out + off;
            const float* xb = x + off;
            #pragma unroll
            for (int r = 0; r < 4; ++r) {
                float h = acc[ct][r] * bsc[o0 + r] + bsh[o0 + r] + xb[r * 7500];
                ob[r * 7500] = fmaxf(h, 0.f);
            }
        }
    }
}

// ---------------------------------------------------------------- launch
extern "C" void kernel_launch(void* const* d_in, const int* in_sizes, int n_in,
                              void* d_out, int out_size, void* d_ws, size_t ws_size,
                              hipStream_t stream) {
    const float* x    = (const float*)d_in[0];
    const float* A    = (const float*)d_in[1];
    const float* GA   = (const float*)d_in[2];
    const float* g_w  = (const float*)d_in[3];
    const float* g_b  = (const float*)d_in[4];
    const float* a_w  = (const float*)d_in[5];
    const float* a_b  = (const float*)d_in[6];
    const float* b_w  = (const float*)d_in[7];
    const float* b_b  = (const float*)d_in[8];
    const float* bn_g = (const float*)d_in[9];
    const float* bn_b = (const float*)d_in[10];
    const float* bn_m = (const float*)d_in[11];
    const float* bn_v = (const float*)d_in[12];
    float* out = (float*)d_out;

    // ws: Mb f32[120000] (480000 B) | atT bf16 (393216 B) | gwb (24576 B)
    // wb2 (12288 B) OVERLAPS the start of atT: k0 writes wb2 -> k1 reads
    // wb2 -> k2 overwrites region with atT -> k3 reads atT. Stream-serial.
    float*    Mb  = (float*)d_ws;
    uint32*   atT = (uint32*)((char*)d_ws + 480000);
    ushort16* wb2 = (ushort16*)((char*)d_ws + 480000);
    uint32*   gwb = (uint32*)((char*)d_ws + 480000 + 393216);

    k0_prep<<<dim3(48), dim3(256), 0, stream>>>(a_w, b_w, g_w, wb2, gwb, Mb);
    k1_attn_logits_mfma<<<dim3(1600), dim3(256), 0, stream>>>(x, wb2, a_b, b_b, Mb);
    k2_softmax<<<dim3(192), dim3(128), 0, stream>>>(Mb, A, GA, atT);
    k3_out<<<dim3(3840), dim3(256), 0, stream>>>(x, atT, (const ushort16*)gwb,
                                                 g_b, bn_g, bn_b, bn_m, bn_v, out);
}